// Round 1
// baseline (351.241 us; speedup 1.0000x reference)
//
#include <hip/hip_runtime.h>

// DomDepResidualLayer: out = relu(h0 + (mixed @ we1^T + b1))
//   enc   = h0 @ we0^T + b0                         [16384,128]
//   acts  = relu(einsum('nd,mkd->mnk', enc, wm)+bm) (never materialized)
//   gate  = softmax(enc @ ws^T + bs, axis=0)        [16384,128]
//   mixed[n,i] = sum_j acts[i,n,j]*gate[n,j]        [16384,128]
// All GEMMs via bf16 MFMA 16x16x32, fp32 accum; residual in fp32.

#define N_TOK   16384
#define EMB     1024
#define MDIM    128

typedef __attribute__((ext_vector_type(8))) short   short8;   // 8 bf16 = 1 MFMA operand frag
typedef __attribute__((ext_vector_type(4))) float   f32x4;
typedef __attribute__((ext_vector_type(4))) float   fv4;
typedef __attribute__((ext_vector_type(4))) unsigned short us4;

static __device__ __forceinline__ unsigned short f2bf(float f) {
    union { float f; unsigned u; } v; v.f = f;
    unsigned r = v.u + 0x7FFFu + ((v.u >> 16) & 1u);   // RNE
    return (unsigned short)(r >> 16);
}
static __device__ __forceinline__ float bf2f(unsigned short h) {
    union { unsigned u; float f; } v; v.u = ((unsigned)h) << 16;
    return v.f;
}

// ---------------- fp32 -> bf16 weight conversion ----------------
__global__ void k_convert(const float* __restrict__ src,
                          unsigned short* __restrict__ dst, int n4) {
    for (int i = blockIdx.x * blockDim.x + threadIdx.x; i < n4;
         i += gridDim.x * blockDim.x) {
        fv4 v = *(const fv4*)(src + (size_t)i * 4);
        us4 o;
        o.x = f2bf(v.x); o.y = f2bf(v.y); o.z = f2bf(v.z); o.w = f2bf(v.w);
        *(us4*)(dst + (size_t)i * 4) = o;
    }
}

// ---------------- enc = h0 @ we0^T + b0  (K=1024, LDS-staged) ----------------
// grid 512: block = 32 tokens x 128 dout. 4 waves: (wd,wt) = (w>>1, w&1)
// wave tile = 64 dout x 16 tok. XOR-swizzled LDS (16B granule ^ (row&7)).
__global__ __launch_bounds__(256) void k_enc(const float* __restrict__ h0,
                                             const unsigned short* __restrict__ we0b,
                                             const float* __restrict__ we0_bias,
                                             unsigned short* __restrict__ encb) {
    __shared__ unsigned short Wt[128 * 128];  // [dout][128k] bf16, swizzled
    __shared__ unsigned short Ht[32 * 128];   // [tok ][128k] bf16, swizzled

    const int tid = threadIdx.x;
    const int lane = tid & 63, w = tid >> 6;
    const int c = lane & 15, g = lane >> 4;
    const int wd = w >> 1, wt = w & 1;
    const int t0 = blockIdx.x * 32;

    f32x4 acc[4] = {};
    for (int ks = 0; ks < 8; ++ks) {
        // stage we0 tile [128][128k]
        #pragma unroll
        for (int it = 0; it < 8; ++it) {
            int m = it * 256 + tid;
            int row = m >> 4, gc = m & 15;
            short8 v = *(const short8*)(we0b + row * 1024 + ks * 128 + gc * 8);
            *(short8*)&Wt[row * 128 + ((gc ^ (row & 7)) * 8)] = v;
        }
        // stage h0 tile [32][128k], fp32 -> bf16
        #pragma unroll
        for (int it = 0; it < 2; ++it) {
            int m = it * 256 + tid;
            int row = m >> 4, gc = m & 15;
            const float* hp = h0 + (size_t)(t0 + row) * 1024 + ks * 128 + gc * 8;
            fv4 v0 = *(const fv4*)hp;
            fv4 v1 = *(const fv4*)(hp + 4);
            short8 ov;
            ov[0] = (short)f2bf(v0.x); ov[1] = (short)f2bf(v0.y);
            ov[2] = (short)f2bf(v0.z); ov[3] = (short)f2bf(v0.w);
            ov[4] = (short)f2bf(v1.x); ov[5] = (short)f2bf(v1.y);
            ov[6] = (short)f2bf(v1.z); ov[7] = (short)f2bf(v1.w);
            *(short8*)&Ht[row * 128 + ((gc ^ (row & 7)) * 8)] = ov;
        }
        __syncthreads();
        #pragma unroll
        for (int s = 0; s < 4; ++s) {
            int gk = s * 4 + g;
            int brow = wt * 16 + c;
            short8 b = *(const short8*)&Ht[brow * 128 + ((gk ^ (brow & 7)) * 8)];
            #pragma unroll
            for (int jf = 0; jf < 4; ++jf) {
                int j = wd * 64 + jf * 16 + c;
                short8 a = *(const short8*)&Wt[j * 128 + ((gk ^ (j & 7)) * 8)];
                acc[jf] = __builtin_amdgcn_mfma_f32_16x16x32_bf16(a, b, acc[jf], 0, 0, 0);
            }
        }
        __syncthreads();
    }
    // epilogue: enc[tok][dout] = acc + bias, store bf16
    const int tokr = t0 + wt * 16 + c;
    #pragma unroll
    for (int f = 0; f < 4; ++f) {
        int d0 = wd * 64 + f * 16 + 4 * g;
        fv4 bi = *(const fv4*)(we0_bias + d0);
        us4 o;
        o.x = f2bf(acc[f][0] + bi.x);
        o.y = f2bf(acc[f][1] + bi.y);
        o.z = f2bf(acc[f][2] + bi.z);
        o.w = f2bf(acc[f][3] + bi.w);
        *(us4*)(encb + (size_t)tokr * 128 + d0) = o;
    }
}

// ---------------- logits^T[m][n] = enc @ ws^T + bs ----------------
// grid 256: block = 64 tokens; wave = 128 m x 16 tok, ws panel from L2.
__global__ __launch_bounds__(256, 2) void k_logits(const unsigned short* __restrict__ encb,
                                                   const unsigned short* __restrict__ wsb,
                                                   const float* __restrict__ ws_bias,
                                                   float* __restrict__ logT) {
    const int tid = threadIdx.x;
    const int lane = tid & 63, w = tid >> 6;
    const int c = lane & 15, g = lane >> 4;
    const int tokr = blockIdx.x * 64 + w * 16 + c;

    short8 a[8][4];
    #pragma unroll
    for (int jf = 0; jf < 8; ++jf)
        #pragma unroll
        for (int s = 0; s < 4; ++s)
            a[jf][s] = *(const short8*)(wsb + (jf * 16 + c) * 128 + s * 32 + g * 8);

    short8 b[4];
    #pragma unroll
    for (int s = 0; s < 4; ++s)
        b[s] = *(const short8*)(encb + (size_t)tokr * 128 + s * 32 + g * 8);

    f32x4 acc[8] = {};
    #pragma unroll
    for (int s = 0; s < 4; ++s)
        #pragma unroll
        for (int jf = 0; jf < 8; ++jf)
            acc[jf] = __builtin_amdgcn_mfma_f32_16x16x32_bf16(a[jf][s], b[s], acc[jf], 0, 0, 0);

    #pragma unroll
    for (int f = 0; f < 8; ++f) {
        int m0 = f * 16 + 4 * g;
        fv4 bi = *(const fv4*)(ws_bias + m0);
        logT[(size_t)(m0 + 0) * N_TOK + tokr] = acc[f][0] + bi.x;
        logT[(size_t)(m0 + 1) * N_TOK + tokr] = acc[f][1] + bi.y;
        logT[(size_t)(m0 + 2) * N_TOK + tokr] = acc[f][2] + bi.z;
        logT[(size_t)(m0 + 3) * N_TOK + tokr] = acc[f][3] + bi.w;
    }
}

// ---------------- gate[n][m] = softmax over n (axis 0), per column m ----------------
// grid 128: one block per column m; reads logT[m][*] coalesced.
__global__ __launch_bounds__(256) void k_softmax0(const float* __restrict__ logT,
                                                  unsigned short* __restrict__ gateb) {
    __shared__ float red[8];
    const int m = blockIdx.x;
    const int tid = threadIdx.x;
    const int lane = tid & 63, wv = tid >> 6;
    const float* row = logT + (size_t)m * N_TOK;

    fv4 v[16];
    float vmax = -3.0e38f;
    #pragma unroll
    for (int it = 0; it < 16; ++it) {
        v[it] = *(const fv4*)(row + it * 1024 + tid * 4);
        vmax = fmaxf(vmax, fmaxf(fmaxf(v[it].x, v[it].y), fmaxf(v[it].z, v[it].w)));
    }
    #pragma unroll
    for (int o = 32; o > 0; o >>= 1) vmax = fmaxf(vmax, __shfl_xor(vmax, o));
    if (lane == 0) red[wv] = vmax;
    __syncthreads();
    const float bmax = fmaxf(fmaxf(red[0], red[1]), fmaxf(red[2], red[3]));

    float s = 0.f;
    #pragma unroll
    for (int it = 0; it < 16; ++it) {
        v[it].x = __expf(v[it].x - bmax); v[it].y = __expf(v[it].y - bmax);
        v[it].z = __expf(v[it].z - bmax); v[it].w = __expf(v[it].w - bmax);
        s += v[it].x + v[it].y + v[it].z + v[it].w;
    }
    #pragma unroll
    for (int o = 32; o > 0; o >>= 1) s += __shfl_xor(s, o);
    if (lane == 0) red[4 + wv] = s;
    __syncthreads();
    const float inv = 1.f / (red[4] + red[5] + red[6] + red[7]);

    #pragma unroll
    for (int it = 0; it < 16; ++it) {
        int t = it * 1024 + tid * 4;
        gateb[(size_t)(t + 0) * MDIM + m] = f2bf(v[it].x * inv);
        gateb[(size_t)(t + 1) * MDIM + m] = f2bf(v[it].y * inv);
        gateb[(size_t)(t + 2) * MDIM + m] = f2bf(v[it].z * inv);
        gateb[(size_t)(t + 3) * MDIM + m] = f2bf(v[it].w * inv);
    }
}

// ---------------- mixed[n][i] = sum_j relu(enc@wm[i]^T + bm)[n][j] * gate[n][j] ----------------
// THE hot kernel (68.7 GF). grid 4096 = 128 modules x 32 token-groups(512).
// Wave: wm[i] panel resident in 128 VGPRs; 8 tiles of 16 tokens; no LDS.
__global__ __launch_bounds__(256, 2) void k_mix(const unsigned short* __restrict__ wmb,
                                                const unsigned short* __restrict__ encb,
                                                const unsigned short* __restrict__ gateb,
                                                const float* __restrict__ wm_bias,
                                                unsigned short* __restrict__ mixedb) {
    const int bid = blockIdx.x;
    const int i = bid >> 5, tg = bid & 31;
    const int tid = threadIdx.x;
    const int lane = tid & 63, w = tid >> 6;
    const int c = lane & 15, g = lane >> 4;

    const unsigned short* wmi = wmb + (size_t)i * 16384;
    short8 a[8][4];
    #pragma unroll
    for (int jf = 0; jf < 8; ++jf)
        #pragma unroll
        for (int s = 0; s < 4; ++s)
            a[jf][s] = *(const short8*)(wmi + (jf * 16 + c) * 128 + s * 32 + g * 8);
    const float* bias = wm_bias + i * 128;

    for (int t = 0; t < 8; ++t) {
        const int tokr = tg * 512 + t * 64 + w * 16 + c;
        const unsigned short* ep = encb + (size_t)tokr * 128;
        short8 b[4];
        #pragma unroll
        for (int s = 0; s < 4; ++s)
            b[s] = *(const short8*)(ep + s * 32 + g * 8);

        f32x4 acc[8] = {};
        #pragma unroll
        for (int s = 0; s < 4; ++s)
            #pragma unroll
            for (int jf = 0; jf < 8; ++jf)
                acc[jf] = __builtin_amdgcn_mfma_f32_16x16x32_bf16(a[jf][s], b[s], acc[jf], 0, 0, 0);

        const unsigned short* gp = gateb + (size_t)tokr * 128;
        float p = 0.f;
        #pragma unroll
        for (int f = 0; f < 8; ++f) {
            int j0 = f * 16 + 4 * g;
            us4 g4 = *(const us4*)(gp + j0);
            fv4 bi = *(const fv4*)(bias + j0);
            p += fmaxf(acc[f][0] + bi.x, 0.f) * bf2f(g4.x);
            p += fmaxf(acc[f][1] + bi.y, 0.f) * bf2f(g4.y);
            p += fmaxf(acc[f][2] + bi.z, 0.f) * bf2f(g4.z);
            p += fmaxf(acc[f][3] + bi.w, 0.f) * bf2f(g4.w);
        }
        p += __shfl_xor(p, 16);
        p += __shfl_xor(p, 32);
        if (lane < 16) mixedb[(size_t)tokr * 128 + i] = f2bf(p);
    }
}

// ---------------- out = relu(mixed @ we1^T + b1 + h0) ----------------
// grid 256 = 8 e-blocks x 32 token-groups(512). we1 e-panel resident per wave.
__global__ __launch_bounds__(256, 2) void k_dec(const unsigned short* __restrict__ we1b,
                                                const unsigned short* __restrict__ mixedb,
                                                const float* __restrict__ we1_bias,
                                                const float* __restrict__ h0,
                                                float* __restrict__ out) {
    const int bid = blockIdx.x;
    const int eb = bid >> 5, tg = bid & 31;
    const int e0 = eb * 128;
    const int tid = threadIdx.x;
    const int lane = tid & 63, w = tid >> 6;
    const int c = lane & 15, g = lane >> 4;

    short8 a[8][4];
    #pragma unroll
    for (int jf = 0; jf < 8; ++jf)
        #pragma unroll
        for (int s = 0; s < 4; ++s)
            a[jf][s] = *(const short8*)(we1b + (size_t)(e0 + jf * 16 + c) * 128 + s * 32 + g * 8);

    for (int t = 0; t < 8; ++t) {
        const int tokr = tg * 512 + t * 64 + w * 16 + c;
        const unsigned short* mp = mixedb + (size_t)tokr * 128;
        short8 b[4];
        #pragma unroll
        for (int s = 0; s < 4; ++s)
            b[s] = *(const short8*)(mp + s * 32 + g * 8);

        f32x4 acc[8] = {};
        #pragma unroll
        for (int s = 0; s < 4; ++s)
            #pragma unroll
            for (int jf = 0; jf < 8; ++jf)
                acc[jf] = __builtin_amdgcn_mfma_f32_16x16x32_bf16(a[jf][s], b[s], acc[jf], 0, 0, 0);

        #pragma unroll
        for (int f = 0; f < 8; ++f) {
            int ej = e0 + f * 16 + 4 * g;
            fv4 bi = *(const fv4*)(we1_bias + ej);
            fv4 h  = *(const fv4*)(h0 + (size_t)tokr * 1024 + ej);
            fv4 o;
            o.x = fmaxf(acc[f][0] + bi.x + h.x, 0.f);
            o.y = fmaxf(acc[f][1] + bi.y + h.y, 0.f);
            o.z = fmaxf(acc[f][2] + bi.z + h.z, 0.f);
            o.w = fmaxf(acc[f][3] + bi.w + h.w, 0.f);
            *(fv4*)(out + (size_t)tokr * 1024 + ej) = o;
        }
    }
}

extern "C" void kernel_launch(void* const* d_in, const int* in_sizes, int n_in,
                              void* d_out, int out_size, void* d_ws, size_t ws_size,
                              hipStream_t stream) {
    const float* h0    = (const float*)d_in[0];
    const float* we0_w = (const float*)d_in[1];
    const float* we0_b = (const float*)d_in[2];
    const float* ws_w  = (const float*)d_in[3];
    const float* ws_b  = (const float*)d_in[4];
    const float* wm_w  = (const float*)d_in[5];
    const float* wm_b  = (const float*)d_in[6];
    const float* we1_w = (const float*)d_in[7];
    const float* we1_b = (const float*)d_in[8];
    float* out = (float*)d_out;

    // workspace layout (~24.6 MB total)
    unsigned short* wmb    = (unsigned short*)d_ws;       // 128*128*128
    unsigned short* we0b   = wmb  + 2097152;              // 128*1024
    unsigned short* we1b   = we0b + 131072;               // 1024*128
    unsigned short* wsb    = we1b + 131072;               // 128*128
    unsigned short* encb   = wsb  + 16384;                // 16384*128
    float*          logT   = (float*)(encb + 2097152);    // [128][16384]
    unsigned short* gateb  = (unsigned short*)(logT + 2097152); // [16384][128]
    unsigned short* mixedb = gateb + 2097152;             // [16384][128]

    k_convert<<<512, 256, 0, stream>>>(wm_w,  wmb,  524288);
    k_convert<<<64,  256, 0, stream>>>(we0_w, we0b, 32768);
    k_convert<<<64,  256, 0, stream>>>(we1_w, we1b, 32768);
    k_convert<<<16,  256, 0, stream>>>(ws_w,  wsb,  4096);

    k_enc<<<512, 256, 0, stream>>>(h0, we0b, we0_b, encb);
    k_logits<<<256, 256, 0, stream>>>(encb, wsb, ws_b, logT);
    k_softmax0<<<128, 256, 0, stream>>>(logT, gateb);
    k_mix<<<4096, 256, 0, stream>>>(wmb, encb, gateb, wm_b, mixedb);
    k_dec<<<256, 256, 0, stream>>>(we1b, mixedb, we1_b, h0, out);
}

// Round 3
// 203.568 us; speedup vs baseline: 1.7254x; 1.7254x over previous
//
#include <hip/hip_runtime.h>

// DomDepResidualLayer: out = relu(h0 + (mixed @ we1^T + b1))
//   enc   = h0 @ we0^T + b0                         [16384,128]
//   acts  = relu(einsum('nd,mkd->mnk', enc, wm)+bm) (never materialized)
//   gate  = softmax(enc @ ws^T + bs, axis=0)        [16384,128]
//   mixed[n,i] = sum_j acts[i,n,j]*gate[n,j]        [16384,128]
// v3: v2 with corrected fragment-tile strides (tile*2048, s*512 — a 16x128
// tile is 2048 bf16), corrected gate q-block read offsets, L2-friendly bid
// decode in k_mix, waves_per_eu(2,2) on k_dec.

#define N_TOK   16384
#define EMB     1024
#define MDIM    128

typedef __attribute__((ext_vector_type(8))) short   short8;   // 8 bf16 = 1 MFMA operand frag
typedef __attribute__((ext_vector_type(4))) float   f32x4;
typedef __attribute__((ext_vector_type(4))) float   fv4;
typedef __attribute__((ext_vector_type(4))) unsigned short us4;

static __device__ __forceinline__ unsigned short f2bf(float f) {
    union { float f; unsigned u; } v; v.f = f;
    unsigned r = v.u + 0x7FFFu + ((v.u >> 16) & 1u);   // RNE
    return (unsigned short)(r >> 16);
}
static __device__ __forceinline__ float bf2f_lo(unsigned u) {  // low bf16 of u32
    union { unsigned u; float f; } v; v.u = u << 16; return v.f;
}
static __device__ __forceinline__ float bf2f_hi(unsigned u) {  // high bf16 of u32
    union { unsigned u; float f; } v; v.u = u & 0xffff0000u; return v.f;
}

// ---------------- fp32 -> bf16 weight conversion ----------------
__global__ void k_convert(const float* __restrict__ src,
                          unsigned short* __restrict__ dst, int n4) {
    for (int i = blockIdx.x * blockDim.x + threadIdx.x; i < n4;
         i += gridDim.x * blockDim.x) {
        fv4 v = *(const fv4*)(src + (size_t)i * 4);
        us4 o;
        o.x = f2bf(v.x); o.y = f2bf(v.y); o.z = f2bf(v.z); o.w = f2bf(v.w);
        *(us4*)(dst + (size_t)i * 4) = o;
    }
}

// Fragment-tiled bf16 layout for a [N,128] matrix X (2048 bf16 per 16-tok tile):
//   offset(tok,d) = (tok>>4)*2048 + (d>>5)*512 + (((d&31)>>3)*16 + (tok&15))*8 + (d&7)
//   i.e. lane=(g*16+c) reads X[tile*16+c][s*32+g*8 .. +7] at tile*2048+s*512+lane*8

// ---------------- enc = h0 @ we0^T + b0  (K=1024, LDS-staged) ----------------
// grid 512: block = 32 tokens x 128 dout. 4 waves: (wd,wt) = (w>>1, w&1)
__global__ __launch_bounds__(256) void k_enc(const float* __restrict__ h0,
                                             const unsigned short* __restrict__ we0b,
                                             const float* __restrict__ we0_bias,
                                             unsigned short* __restrict__ encT) {
    __shared__ unsigned short Wt[128 * 128];  // [dout][128k] bf16, swizzled
    __shared__ unsigned short Ht[32 * 128];   // [tok ][128k] bf16, swizzled

    const int tid = threadIdx.x;
    const int lane = tid & 63, w = tid >> 6;
    const int c = lane & 15, g = lane >> 4;
    const int wd = w >> 1, wt = w & 1;
    const int t0 = blockIdx.x * 32;

    f32x4 acc[4] = {};
    for (int ks = 0; ks < 8; ++ks) {
        #pragma unroll
        for (int it = 0; it < 8; ++it) {
            int m = it * 256 + tid;
            int row = m >> 4, gc = m & 15;
            short8 v = *(const short8*)(we0b + row * 1024 + ks * 128 + gc * 8);
            *(short8*)&Wt[row * 128 + ((gc ^ (row & 7)) * 8)] = v;
        }
        #pragma unroll
        for (int it = 0; it < 2; ++it) {
            int m = it * 256 + tid;
            int row = m >> 4, gc = m & 15;
            const float* hp = h0 + (size_t)(t0 + row) * 1024 + ks * 128 + gc * 8;
            fv4 v0 = *(const fv4*)hp;
            fv4 v1 = *(const fv4*)(hp + 4);
            short8 ov;
            ov[0] = (short)f2bf(v0.x); ov[1] = (short)f2bf(v0.y);
            ov[2] = (short)f2bf(v0.z); ov[3] = (short)f2bf(v0.w);
            ov[4] = (short)f2bf(v1.x); ov[5] = (short)f2bf(v1.y);
            ov[6] = (short)f2bf(v1.z); ov[7] = (short)f2bf(v1.w);
            *(short8*)&Ht[row * 128 + ((gc ^ (row & 7)) * 8)] = ov;
        }
        __syncthreads();
        #pragma unroll
        for (int s = 0; s < 4; ++s) {
            int gk = s * 4 + g;
            int brow = wt * 16 + c;
            short8 b = *(const short8*)&Ht[brow * 128 + ((gk ^ (brow & 7)) * 8)];
            #pragma unroll
            for (int jf = 0; jf < 4; ++jf) {
                int j = wd * 64 + jf * 16 + c;
                short8 a = *(const short8*)&Wt[j * 128 + ((gk ^ (j & 7)) * 8)];
                acc[jf] = __builtin_amdgcn_mfma_f32_16x16x32_bf16(a, b, acc[jf], 0, 0, 0);
            }
        }
        __syncthreads();
    }
    // epilogue -> fragment-tiled encT
    const int tile = blockIdx.x * 2 + wt;
    #pragma unroll
    for (int f = 0; f < 4; ++f) {
        int d0 = wd * 64 + f * 16 + 4 * g;
        int s = wd * 2 + (f >> 1);
        int chunk = ((f & 1) ? 2 : 0) + (g >> 1);
        int e = (g & 1) * 4;
        fv4 bi = *(const fv4*)(we0_bias + d0);
        us4 o;
        o.x = f2bf(acc[f][0] + bi.x);
        o.y = f2bf(acc[f][1] + bi.y);
        o.z = f2bf(acc[f][2] + bi.z);
        o.w = f2bf(acc[f][3] + bi.w);
        *(us4*)(encT + (size_t)tile * 2048 + s * 512 + (chunk * 16 + c) * 8 + e) = o;
    }
}

// ---------------- logits^T[m][n] = enc @ ws^T + bs ----------------
__global__ __launch_bounds__(256, 2) void k_logits(const unsigned short* __restrict__ encT,
                                                   const unsigned short* __restrict__ wsb,
                                                   const float* __restrict__ ws_bias,
                                                   float* __restrict__ logT) {
    const int tid = threadIdx.x;
    const int lane = tid & 63, w = tid >> 6;
    const int c = lane & 15, g = lane >> 4;
    const int tokr = blockIdx.x * 64 + w * 16 + c;
    const int tile = blockIdx.x * 4 + w;

    short8 a[8][4];
    #pragma unroll
    for (int jf = 0; jf < 8; ++jf)
        #pragma unroll
        for (int s = 0; s < 4; ++s) {
            a[jf][s] = *(const short8*)(wsb + (jf * 16 + c) * 128 + s * 32 + g * 8);
            asm volatile("" : "+v"(a[jf][s]));
        }

    short8 b[4];
    #pragma unroll
    for (int s = 0; s < 4; ++s)
        b[s] = *(const short8*)(encT + (size_t)tile * 2048 + s * 512 + lane * 8);

    f32x4 acc[8] = {};
    #pragma unroll
    for (int s = 0; s < 4; ++s)
        #pragma unroll
        for (int jf = 0; jf < 8; ++jf)
            acc[jf] = __builtin_amdgcn_mfma_f32_16x16x32_bf16(a[jf][s], b[s], acc[jf], 0, 0, 0);

    #pragma unroll
    for (int f = 0; f < 8; ++f) {
        int m0 = f * 16 + 4 * g;
        fv4 bi = *(const fv4*)(ws_bias + m0);
        logT[(size_t)(m0 + 0) * N_TOK + tokr] = acc[f][0] + bi.x;
        logT[(size_t)(m0 + 1) * N_TOK + tokr] = acc[f][1] + bi.y;
        logT[(size_t)(m0 + 2) * N_TOK + tokr] = acc[f][2] + bi.z;
        logT[(size_t)(m0 + 3) * N_TOK + tokr] = acc[f][3] + bi.w;
    }
}

// ---------------- gate = softmax over axis 0, per column m ----------------
// gateT layout per tile (16 tok x 128 j): value (tok, j=f*16+4g+rr) at
//   tile*2048 + (f>>1)*512 + (g*16 + (tok&15))*8 + (f&1)*4 + rr
__global__ __launch_bounds__(256) void k_softmax0(const float* __restrict__ logT,
                                                  unsigned short* __restrict__ gateT) {
    __shared__ float red[8];
    const int m = blockIdx.x;
    const int tid = threadIdx.x;
    const int lane = tid & 63, wv = tid >> 6;
    const float* row = logT + (size_t)m * N_TOK;

    fv4 v[16];
    float vmax = -3.0e38f;
    #pragma unroll
    for (int it = 0; it < 16; ++it) {
        v[it] = *(const fv4*)(row + it * 1024 + tid * 4);
        vmax = fmaxf(vmax, fmaxf(fmaxf(v[it].x, v[it].y), fmaxf(v[it].z, v[it].w)));
    }
    #pragma unroll
    for (int o = 32; o > 0; o >>= 1) vmax = fmaxf(vmax, __shfl_xor(vmax, o));
    if (lane == 0) red[wv] = vmax;
    __syncthreads();
    const float bmax = fmaxf(fmaxf(red[0], red[1]), fmaxf(red[2], red[3]));

    float s = 0.f;
    #pragma unroll
    for (int it = 0; it < 16; ++it) {
        v[it].x = __expf(v[it].x - bmax); v[it].y = __expf(v[it].y - bmax);
        v[it].z = __expf(v[it].z - bmax); v[it].w = __expf(v[it].w - bmax);
        s += v[it].x + v[it].y + v[it].z + v[it].w;
    }
    #pragma unroll
    for (int o = 32; o > 0; o >>= 1) s += __shfl_xor(s, o);
    if (lane == 0) red[4 + wv] = s;
    __syncthreads();
    const float inv = 1.f / (red[4] + red[5] + red[6] + red[7]);

    const int q  = m >> 5;
    const int w8 = ((m >> 4) & 1) * 4 + (m & 3);
    const int gl = ((m & 15) >> 2) * 16;
    #pragma unroll
    for (int it = 0; it < 16; ++it) {
        int t = it * 1024 + tid * 4;
        float pv[4] = { v[it].x * inv, v[it].y * inv, v[it].z * inv, v[it].w * inv };
        #pragma unroll
        for (int k = 0; k < 4; ++k) {
            int tok = t + k;
            gateT[(size_t)(tok >> 4) * 2048 + q * 512 + (gl + (tok & 15)) * 8 + w8] = f2bf(pv[k]);
        }
    }
}

// ---------------- mixed[n][i] = sum_j relu(enc@wm[i]^T + bm)[n][j] * gate[n][j] ----------------
// THE hot kernel. grid 1024: i = bid&127 (fast -> blocks sharing tg co-resident),
// tg = bid>>7 (2048 tokens each). Wave: full wm[i] panel pinned in VGPRs.
__global__ __launch_bounds__(256)
__attribute__((amdgpu_waves_per_eu(2, 2)))
void k_mix(const unsigned short* __restrict__ wmb,
           const unsigned short* __restrict__ encT,
           const unsigned short* __restrict__ gateT,
           const float* __restrict__ wm_bias,
           unsigned short* __restrict__ mixT) {
    const int bid = blockIdx.x;
    const int i = bid & 127, tg = bid >> 7;
    const int tid = threadIdx.x;
    const int lane = tid & 63, w = tid >> 6;
    const int c = lane & 15, g = lane >> 4;

    const unsigned short* wmi = wmb + (size_t)i * 16384;
    short8 a[8][4];
    #pragma unroll
    for (int jf = 0; jf < 8; ++jf)
        #pragma unroll
        for (int s = 0; s < 4; ++s) {
            a[jf][s] = *(const short8*)(wmi + (jf * 16 + c) * 128 + s * 32 + g * 8);
            asm volatile("" : "+v"(a[jf][s]));
        }
    f32x4 bias4[8];
    #pragma unroll
    for (int f = 0; f < 8; ++f) {
        bias4[f] = *(const f32x4*)(wm_bias + i * 128 + f * 16 + 4 * g);
        asm volatile("" : "+v"(bias4[f]));
    }

    const int si = i >> 5, ch = (i & 31) >> 3, ei = i & 7;  // mixT coords for module i

    for (int rr = 0; rr < 32; ++rr) {
        const int tile = tg * 128 + rr * 4 + w;
        const unsigned short* ep = encT + (size_t)tile * 2048 + lane * 8;
        short8 b0 = *(const short8*)(ep);
        short8 b1 = *(const short8*)(ep + 512);
        short8 b2 = *(const short8*)(ep + 1024);
        short8 b3 = *(const short8*)(ep + 1536);
        const unsigned* gp = (const unsigned*)(gateT + (size_t)tile * 2048) + lane * 4;
        uint4 G0 = *(const uint4*)(gp);          // f=0,1
        uint4 G1 = *(const uint4*)(gp + 256);    // f=2,3
        uint4 G2 = *(const uint4*)(gp + 512);    // f=4,5
        uint4 G3 = *(const uint4*)(gp + 768);    // f=6,7

        f32x4 acc[8];
        #pragma unroll
        for (int jf = 0; jf < 8; ++jf)
            acc[jf] = __builtin_amdgcn_mfma_f32_16x16x32_bf16(a[jf][0], b0, bias4[jf], 0, 0, 0);
        #pragma unroll
        for (int jf = 0; jf < 8; ++jf)
            acc[jf] = __builtin_amdgcn_mfma_f32_16x16x32_bf16(a[jf][1], b1, acc[jf], 0, 0, 0);
        #pragma unroll
        for (int jf = 0; jf < 8; ++jf)
            acc[jf] = __builtin_amdgcn_mfma_f32_16x16x32_bf16(a[jf][2], b2, acc[jf], 0, 0, 0);
        #pragma unroll
        for (int jf = 0; jf < 8; ++jf)
            acc[jf] = __builtin_amdgcn_mfma_f32_16x16x32_bf16(a[jf][3], b3, acc[jf], 0, 0, 0);

        // epilogue: p = sum_j relu(acc)*gate, 4 independent chains
        float p0 = 0.f, p1 = 0.f, p2 = 0.f, p3 = 0.f;
        #define EPI(F, GA, GB) {                                        \
            p0 += fmaxf(acc[F][0], 0.f) * bf2f_lo(GA);                  \
            p1 += fmaxf(acc[F][1], 0.f) * bf2f_hi(GA);                  \
            p2 += fmaxf(acc[F][2], 0.f) * bf2f_lo(GB);                  \
            p3 += fmaxf(acc[F][3], 0.f) * bf2f_hi(GB);                  \
        }
        EPI(0, G0.x, G0.y) EPI(1, G0.z, G0.w)
        EPI(2, G1.x, G1.y) EPI(3, G1.z, G1.w)
        EPI(4, G2.x, G2.y) EPI(5, G2.z, G2.w)
        EPI(6, G3.x, G3.y) EPI(7, G3.z, G3.w)
        #undef EPI
        float p = (p0 + p1) + (p2 + p3);
        p += __shfl_xor(p, 16);
        p += __shfl_xor(p, 32);
        if (lane < 16)
            mixT[(size_t)tile * 2048 + si * 512 + (ch * 16 + lane) * 8 + ei] = f2bf(p);
    }
}

// ---------------- out = relu(mixed @ we1^T + b1 + h0) ----------------
__global__ __launch_bounds__(256)
__attribute__((amdgpu_waves_per_eu(2, 2)))
void k_dec(const unsigned short* __restrict__ we1b,
           const unsigned short* __restrict__ mixT,
           const float* __restrict__ we1_bias,
           const float* __restrict__ h0,
           float* __restrict__ out) {
    const int bid = blockIdx.x;
    const int eb = bid >> 5, tg = bid & 31;
    const int e0 = eb * 128;
    const int tid = threadIdx.x;
    const int lane = tid & 63, w = tid >> 6;
    const int c = lane & 15, g = lane >> 4;

    short8 a[8][4];
    #pragma unroll
    for (int jf = 0; jf < 8; ++jf)
        #pragma unroll
        for (int s = 0; s < 4; ++s) {
            a[jf][s] = *(const short8*)(we1b + (size_t)(e0 + jf * 16 + c) * 128 + s * 32 + g * 8);
            asm volatile("" : "+v"(a[jf][s]));
        }

    for (int t = 0; t < 8; ++t) {
        const int tokr = tg * 512 + t * 64 + w * 16 + c;
        const int tile = tg * 32 + t * 4 + w;
        const unsigned short* mp = mixT + (size_t)tile * 2048 + lane * 8;
        short8 b[4];
        #pragma unroll
        for (int s = 0; s < 4; ++s)
            b[s] = *(const short8*)(mp + s * 512);

        f32x4 acc[8] = {};
        #pragma unroll
        for (int s = 0; s < 4; ++s)
            #pragma unroll
            for (int jf = 0; jf < 8; ++jf)
                acc[jf] = __builtin_amdgcn_mfma_f32_16x16x32_bf16(a[jf][s], b[s], acc[jf], 0, 0, 0);

        #pragma unroll
        for (int f = 0; f < 8; ++f) {
            int ej = e0 + f * 16 + 4 * g;
            fv4 bi = *(const fv4*)(we1_bias + ej);
            fv4 h  = *(const fv4*)(h0 + (size_t)tokr * 1024 + ej);
            fv4 o;
            o.x = fmaxf(acc[f][0] + bi.x + h.x, 0.f);
            o.y = fmaxf(acc[f][1] + bi.y + h.y, 0.f);
            o.z = fmaxf(acc[f][2] + bi.z + h.z, 0.f);
            o.w = fmaxf(acc[f][3] + bi.w + h.w, 0.f);
            *(fv4*)(out + (size_t)tokr * 1024 + ej) = o;
        }
    }
}

extern "C" void kernel_launch(void* const* d_in, const int* in_sizes, int n_in,
                              void* d_out, int out_size, void* d_ws, size_t ws_size,
                              hipStream_t stream) {
    const float* h0    = (const float*)d_in[0];
    const float* we0_w = (const float*)d_in[1];
    const float* we0_b = (const float*)d_in[2];
    const float* ws_w  = (const float*)d_in[3];
    const float* ws_b  = (const float*)d_in[4];
    const float* wm_w  = (const float*)d_in[5];
    const float* wm_b  = (const float*)d_in[6];
    const float* we1_w = (const float*)d_in[7];
    const float* we1_b = (const float*)d_in[8];
    float* out = (float*)d_out;

    unsigned short* wmb   = (unsigned short*)d_ws;      // 128*128*128
    unsigned short* we0b  = wmb  + 2097152;             // 128*1024
    unsigned short* we1b  = we0b + 131072;              // 1024*128
    unsigned short* wsb   = we1b + 131072;              // 128*128
    unsigned short* encT  = wsb  + 16384;               // 16384*128 (tiled)
    float*          logT  = (float*)(encT + 2097152);   // [128][16384]
    unsigned short* gateT = (unsigned short*)(logT + 2097152); // 16384*128 (tiled)
    unsigned short* mixT  = gateT + 2097152;            // 16384*128 (tiled)

    k_convert<<<512, 256, 0, stream>>>(wm_w,  wmb,  524288);
    k_convert<<<64,  256, 0, stream>>>(we0_w, we0b, 32768);
    k_convert<<<64,  256, 0, stream>>>(we1_w, we1b, 32768);
    k_convert<<<16,  256, 0, stream>>>(ws_w,  wsb,  4096);

    k_enc<<<512, 256, 0, stream>>>(h0, we0b, we0_b, encT);
    k_logits<<<256, 256, 0, stream>>>(encT, wsb, ws_b, logT);
    k_softmax0<<<128, 256, 0, stream>>>(logT, gateT);
    k_mix<<<1024, 256, 0, stream>>>(wmb, encT, gateT, wm_b, mixT);
    k_dec<<<256, 256, 0, stream>>>(we1b, mixT, we1_b, h0, out);
}

// Round 4
// 185.612 us; speedup vs baseline: 1.8923x; 1.0967x over previous
//
#include <hip/hip_runtime.h>

// DomDepResidualLayer: out = relu(h0 + (mixed @ we1^T + b1))
//   enc   = h0 @ we0^T + b0                         [16384,128]
//   acts  = relu(einsum('nd,mkd->mnk', enc, wm)+bm) (never materialized)
//   gate  = softmax(enc @ ws^T + bs, axis=0)        [16384,128]
//   mixed[n,i] = sum_j acts[i,n,j]*gate[n,j]        [16384,128]
// v5: k_mix software-pipelined (b-frag ping-pong prefetch, early G loads);
// logits fused into k_enc (LDS enc tile); single fused convert kernel;
// k_dec at 512 blocks with early h0 loads.

#define N_TOK   16384
#define EMB     1024
#define MDIM    128

typedef __attribute__((ext_vector_type(8))) short   short8;   // 8 bf16 = 1 MFMA frag
typedef __attribute__((ext_vector_type(4))) float   f32x4;
typedef __attribute__((ext_vector_type(4))) float   fv4;
typedef __attribute__((ext_vector_type(4))) unsigned short us4;

static __device__ __forceinline__ unsigned short f2bf(float f) {
    union { float f; unsigned u; } v; v.f = f;
    unsigned r = v.u + 0x7FFFu + ((v.u >> 16) & 1u);   // RNE
    return (unsigned short)(r >> 16);
}
static __device__ __forceinline__ float bf2f_lo(unsigned u) {
    union { unsigned u; float f; } v; v.u = u << 16; return v.f;
}
static __device__ __forceinline__ float bf2f_hi(unsigned u) {
    union { unsigned u; float f; } v; v.u = u & 0xffff0000u; return v.f;
}

// ---------------- fused fp32 -> bf16 conversion of all weights ----------------
// dst regions are contiguous in d_ws: wmb | we0b | we1b | wsb
__global__ void k_convert_all(const float* __restrict__ wm_w,
                              const float* __restrict__ we0_w,
                              const float* __restrict__ we1_w,
                              const float* __restrict__ ws_w,
                              unsigned short* __restrict__ dst) {
    const int NFV4 = 593920;  // total fv4 groups
    for (int i = blockIdx.x * blockDim.x + threadIdx.x; i < NFV4;
         i += gridDim.x * blockDim.x) {
        const float* src;
        if (i < 524288)       src = wm_w  + (size_t)i * 4;
        else if (i < 557056)  src = we0_w + (size_t)(i - 524288) * 4;
        else if (i < 589824)  src = we1_w + (size_t)(i - 557056) * 4;
        else                  src = ws_w  + (size_t)(i - 589824) * 4;
        fv4 v = *(const fv4*)src;
        us4 o;
        o.x = f2bf(v.x); o.y = f2bf(v.y); o.z = f2bf(v.z); o.w = f2bf(v.w);
        *(us4*)(dst + (size_t)i * 4) = o;
    }
}

// Fragment-tiled bf16 layout for a [N,128] matrix X (2048 bf16 per 16-tok tile):
//   offset(tok,d) = (tok>>4)*2048 + (d>>5)*512 + (((d&31)>>3)*16 + (tok&15))*8 + (d&7)

// ---------------- enc = h0 @ we0^T + b0, fused logits^T = enc @ ws^T + bs ----------------
// grid 512: block = 32 tokens x 128 dout. 4 waves: (wd,wt) = (w>>1, w&1)
__global__ __launch_bounds__(256) void k_enc(const float* __restrict__ h0,
                                             const unsigned short* __restrict__ we0b,
                                             const unsigned short* __restrict__ wsb,
                                             const float* __restrict__ we0_bias,
                                             const float* __restrict__ ws_bias,
                                             unsigned short* __restrict__ encT,
                                             float* __restrict__ logT) {
    __shared__ unsigned short Wt[128 * 128];  // we0 tile, swizzled
    __shared__ unsigned short Ht[32 * 128];   // h0 tile, swizzled
    __shared__ unsigned short Et[32 * 128];   // enc result tile, swizzled

    const int tid = threadIdx.x;
    const int lane = tid & 63, w = tid >> 6;
    const int c = lane & 15, g = lane >> 4;
    const int wd = w >> 1, wt = w & 1;
    const int t0 = blockIdx.x * 32;

    f32x4 acc[4] = {};
    for (int ks = 0; ks < 8; ++ks) {
        #pragma unroll
        for (int it = 0; it < 8; ++it) {
            int m = it * 256 + tid;
            int row = m >> 4, gc = m & 15;
            short8 v = *(const short8*)(we0b + row * 1024 + ks * 128 + gc * 8);
            *(short8*)&Wt[row * 128 + ((gc ^ (row & 7)) * 8)] = v;
        }
        #pragma unroll
        for (int it = 0; it < 2; ++it) {
            int m = it * 256 + tid;
            int row = m >> 4, gc = m & 15;
            const float* hp = h0 + (size_t)(t0 + row) * 1024 + ks * 128 + gc * 8;
            fv4 v0 = *(const fv4*)hp;
            fv4 v1 = *(const fv4*)(hp + 4);
            short8 ov;
            ov[0] = (short)f2bf(v0.x); ov[1] = (short)f2bf(v0.y);
            ov[2] = (short)f2bf(v0.z); ov[3] = (short)f2bf(v0.w);
            ov[4] = (short)f2bf(v1.x); ov[5] = (short)f2bf(v1.y);
            ov[6] = (short)f2bf(v1.z); ov[7] = (short)f2bf(v1.w);
            *(short8*)&Ht[row * 128 + ((gc ^ (row & 7)) * 8)] = ov;
        }
        __syncthreads();
        #pragma unroll
        for (int s = 0; s < 4; ++s) {
            int gk = s * 4 + g;
            int brow = wt * 16 + c;
            short8 b = *(const short8*)&Ht[brow * 128 + ((gk ^ (brow & 7)) * 8)];
            #pragma unroll
            for (int jf = 0; jf < 4; ++jf) {
                int j = wd * 64 + jf * 16 + c;
                short8 a = *(const short8*)&Wt[j * 128 + ((gk ^ (j & 7)) * 8)];
                acc[jf] = __builtin_amdgcn_mfma_f32_16x16x32_bf16(a, b, acc[jf], 0, 0, 0);
            }
        }
        __syncthreads();
    }
    // epilogue: enc -> global encT (fragment-tiled) + LDS Et (swizzled)
    const int tile = blockIdx.x * 2 + wt;
    const int erow = wt * 16 + c;
    #pragma unroll
    for (int f = 0; f < 4; ++f) {
        int d0 = wd * 64 + f * 16 + 4 * g;
        int s = wd * 2 + (f >> 1);
        int chunk = ((f & 1) ? 2 : 0) + (g >> 1);
        int e = (g & 1) * 4;
        fv4 bi = *(const fv4*)(we0_bias + d0);
        us4 o;
        o.x = f2bf(acc[f][0] + bi.x);
        o.y = f2bf(acc[f][1] + bi.y);
        o.z = f2bf(acc[f][2] + bi.z);
        o.w = f2bf(acc[f][3] + bi.w);
        *(us4*)(encT + (size_t)tile * 2048 + s * 512 + (chunk * 16 + c) * 8 + e) = o;
        int cg = d0 >> 3, off = d0 & 7;
        *(us4*)&Et[erow * 128 + ((cg ^ (erow & 7)) * 8) + off] = o;
    }
    __syncthreads();

    // fused logits: wave (wd,wt) computes m in [wd*64, wd*64+64) for tokens wt-half
    short8 al[4][4];
    #pragma unroll
    for (int jf = 0; jf < 4; ++jf)
        #pragma unroll
        for (int s = 0; s < 4; ++s)
            al[jf][s] = *(const short8*)(wsb + (wd * 64 + jf * 16 + c) * 128 + s * 32 + g * 8);
    short8 bl[4];
    #pragma unroll
    for (int s = 0; s < 4; ++s) {
        int cg2 = s * 4 + g;
        bl[s] = *(const short8*)&Et[erow * 128 + ((cg2 ^ (erow & 7)) * 8)];
    }
    f32x4 acc2[4] = {};
    #pragma unroll
    for (int s = 0; s < 4; ++s)
        #pragma unroll
        for (int jf = 0; jf < 4; ++jf)
            acc2[jf] = __builtin_amdgcn_mfma_f32_16x16x32_bf16(al[jf][s], bl[s], acc2[jf], 0, 0, 0);
    const int tokc = t0 + wt * 16 + c;
    #pragma unroll
    for (int jf = 0; jf < 4; ++jf) {
        int m0 = wd * 64 + jf * 16 + 4 * g;
        fv4 bs = *(const fv4*)(ws_bias + m0);
        logT[(size_t)(m0 + 0) * N_TOK + tokc] = acc2[jf][0] + bs.x;
        logT[(size_t)(m0 + 1) * N_TOK + tokc] = acc2[jf][1] + bs.y;
        logT[(size_t)(m0 + 2) * N_TOK + tokc] = acc2[jf][2] + bs.z;
        logT[(size_t)(m0 + 3) * N_TOK + tokc] = acc2[jf][3] + bs.w;
    }
}

// ---------------- gate = softmax over axis 0, per column m ----------------
__global__ __launch_bounds__(256) void k_softmax0(const float* __restrict__ logT,
                                                  unsigned short* __restrict__ gateT) {
    __shared__ float red[8];
    const int m = blockIdx.x;
    const int tid = threadIdx.x;
    const int lane = tid & 63, wv = tid >> 6;
    const float* row = logT + (size_t)m * N_TOK;

    fv4 v[16];
    float vmax = -3.0e38f;
    #pragma unroll
    for (int it = 0; it < 16; ++it) {
        v[it] = *(const fv4*)(row + it * 1024 + tid * 4);
        vmax = fmaxf(vmax, fmaxf(fmaxf(v[it].x, v[it].y), fmaxf(v[it].z, v[it].w)));
    }
    #pragma unroll
    for (int o = 32; o > 0; o >>= 1) vmax = fmaxf(vmax, __shfl_xor(vmax, o));
    if (lane == 0) red[wv] = vmax;
    __syncthreads();
    const float bmax = fmaxf(fmaxf(red[0], red[1]), fmaxf(red[2], red[3]));

    float s = 0.f;
    #pragma unroll
    for (int it = 0; it < 16; ++it) {
        v[it].x = __expf(v[it].x - bmax); v[it].y = __expf(v[it].y - bmax);
        v[it].z = __expf(v[it].z - bmax); v[it].w = __expf(v[it].w - bmax);
        s += v[it].x + v[it].y + v[it].z + v[it].w;
    }
    #pragma unroll
    for (int o = 32; o > 0; o >>= 1) s += __shfl_xor(s, o);
    if (lane == 0) red[4 + wv] = s;
    __syncthreads();
    const float inv = 1.f / (red[4] + red[5] + red[6] + red[7]);

    const int q  = m >> 5;
    const int w8 = ((m >> 4) & 1) * 4 + (m & 3);
    const int gl = ((m & 15) >> 2) * 16;
    #pragma unroll
    for (int it = 0; it < 16; ++it) {
        int t = it * 1024 + tid * 4;
        float pv[4] = { v[it].x * inv, v[it].y * inv, v[it].z * inv, v[it].w * inv };
        #pragma unroll
        for (int k = 0; k < 4; ++k) {
            int tok = t + k;
            gateT[(size_t)(tok >> 4) * 2048 + q * 512 + (gl + (tok & 15)) * 8 + w8] = f2bf(pv[k]);
        }
    }
}

// ---------------- mixed[n][i] = sum_j relu(enc@wm[i]^T + bm)[n][j] * gate[n][j] ----------------
// THE hot kernel. grid 1024: i = bid&127, tg = bid>>7 (2048 tokens).
// Pinned resident wm panel; software pipeline: next-tile b prefetch (ping-pong),
// current-tile gate loads hoisted above the MFMA block.
__global__ __launch_bounds__(256)
__attribute__((amdgpu_waves_per_eu(2, 2)))
void k_mix(const unsigned short* __restrict__ wmb,
           const unsigned short* __restrict__ encT,
           const unsigned short* __restrict__ gateT,
           const float* __restrict__ wm_bias,
           unsigned short* __restrict__ mixT) {
    const int bid = blockIdx.x;
    const int i = bid & 127, tg = bid >> 7;
    const int tid = threadIdx.x;
    const int lane = tid & 63, w = tid >> 6;
    const int c = lane & 15, g = lane >> 4;

    const unsigned short* wmi = wmb + (size_t)i * 16384;
    short8 a[8][4];
    #pragma unroll
    for (int jf = 0; jf < 8; ++jf)
        #pragma unroll
        for (int s = 0; s < 4; ++s) {
            a[jf][s] = *(const short8*)(wmi + (jf * 16 + c) * 128 + s * 32 + g * 8);
            asm volatile("" : "+v"(a[jf][s]));
        }
    f32x4 bias4[8];
    #pragma unroll
    for (int f = 0; f < 8; ++f) {
        bias4[f] = *(const f32x4*)(wm_bias + i * 128 + f * 16 + 4 * g);
        asm volatile("" : "+v"(bias4[f]));
    }

    const int si = i >> 5, ch = (i & 31) >> 3, ei = i & 7;

    // prologue: b-frags for rr=0
    short8 b[4];
    {
        const unsigned short* ep = encT + (size_t)(tg * 128 + w) * 2048 + lane * 8;
        b[0] = *(const short8*)(ep);
        b[1] = *(const short8*)(ep + 512);
        b[2] = *(const short8*)(ep + 1024);
        b[3] = *(const short8*)(ep + 1536);
    }

    #pragma unroll 2
    for (int rr = 0; rr < 32; ++rr) {
        const int tile = tg * 128 + rr * 4 + w;
        // prefetch next tile's b-frags (clamped on last iter)
        const int nrr = (rr < 31) ? rr + 1 : 31;
        const unsigned short* epn = encT + (size_t)(tg * 128 + nrr * 4 + w) * 2048 + lane * 8;
        short8 nb0 = *(const short8*)(epn);
        short8 nb1 = *(const short8*)(epn + 512);
        short8 nb2 = *(const short8*)(epn + 1024);
        short8 nb3 = *(const short8*)(epn + 1536);
        // current tile's gate (consumed ~160cy later in epilogue)
        const unsigned* gp = (const unsigned*)(gateT + (size_t)tile * 2048) + lane * 4;
        uint4 G0 = *(const uint4*)(gp);
        uint4 G1 = *(const uint4*)(gp + 256);
        uint4 G2 = *(const uint4*)(gp + 512);
        uint4 G3 = *(const uint4*)(gp + 768);

        f32x4 acc[8];
        #pragma unroll
        for (int jf = 0; jf < 8; ++jf)
            acc[jf] = __builtin_amdgcn_mfma_f32_16x16x32_bf16(a[jf][0], b[0], bias4[jf], 0, 0, 0);
        #pragma unroll
        for (int jf = 0; jf < 8; ++jf)
            acc[jf] = __builtin_amdgcn_mfma_f32_16x16x32_bf16(a[jf][1], b[1], acc[jf], 0, 0, 0);
        #pragma unroll
        for (int jf = 0; jf < 8; ++jf)
            acc[jf] = __builtin_amdgcn_mfma_f32_16x16x32_bf16(a[jf][2], b[2], acc[jf], 0, 0, 0);
        #pragma unroll
        for (int jf = 0; jf < 8; ++jf)
            acc[jf] = __builtin_amdgcn_mfma_f32_16x16x32_bf16(a[jf][3], b[3], acc[jf], 0, 0, 0);

        float p0 = 0.f, p1 = 0.f, p2 = 0.f, p3 = 0.f;
        #define EPI(F, GA, GB) {                                        \
            p0 += fmaxf(acc[F][0], 0.f) * bf2f_lo(GA);                  \
            p1 += fmaxf(acc[F][1], 0.f) * bf2f_hi(GA);                  \
            p2 += fmaxf(acc[F][2], 0.f) * bf2f_lo(GB);                  \
            p3 += fmaxf(acc[F][3], 0.f) * bf2f_hi(GB);                  \
        }
        EPI(0, G0.x, G0.y) EPI(1, G0.z, G0.w)
        EPI(2, G1.x, G1.y) EPI(3, G1.z, G1.w)
        EPI(4, G2.x, G2.y) EPI(5, G2.z, G2.w)
        EPI(6, G3.x, G3.y) EPI(7, G3.z, G3.w)
        #undef EPI
        float p = (p0 + p1) + (p2 + p3);
        p += __shfl_xor(p, 16);
        p += __shfl_xor(p, 32);
        if (lane < 16)
            mixT[(size_t)tile * 2048 + si * 512 + (ch * 16 + lane) * 8 + ei] = f2bf(p);

        b[0] = nb0; b[1] = nb1; b[2] = nb2; b[3] = nb3;
    }
}

// ---------------- out = relu(mixed @ we1^T + b1 + h0) ----------------
// grid 512 = 8 eb x 64 tg (256 tokens each); early h0 loads per tile.
__global__ __launch_bounds__(256)
__attribute__((amdgpu_waves_per_eu(2, 2)))
void k_dec(const unsigned short* __restrict__ we1b,
           const unsigned short* __restrict__ mixT,
           const float* __restrict__ we1_bias,
           const float* __restrict__ h0,
           float* __restrict__ out) {
    const int bid = blockIdx.x;
    const int eb = bid & 7, tg = bid >> 3;
    const int e0 = eb * 128;
    const int tid = threadIdx.x;
    const int lane = tid & 63, w = tid >> 6;
    const int c = lane & 15, g = lane >> 4;

    short8 a[8][4];
    #pragma unroll
    for (int jf = 0; jf < 8; ++jf)
        #pragma unroll
        for (int s = 0; s < 4; ++s) {
            a[jf][s] = *(const short8*)(we1b + (size_t)(e0 + jf * 16 + c) * 128 + s * 32 + g * 8);
            asm volatile("" : "+v"(a[jf][s]));
        }
    fv4 bi[8];
    #pragma unroll
    for (int f = 0; f < 8; ++f)
        bi[f] = *(const fv4*)(we1_bias + e0 + f * 16 + 4 * g);

    #pragma unroll 1
    for (int t = 0; t < 4; ++t) {
        const int tokr = tg * 256 + t * 64 + w * 16 + c;
        const int tile = tg * 16 + t * 4 + w;
        // issue h0 loads first (HBM, longest latency)
        fv4 h[8];
        #pragma unroll
        for (int f = 0; f < 8; ++f)
            h[f] = *(const fv4*)(h0 + (size_t)tokr * 1024 + e0 + f * 16 + 4 * g);
        const unsigned short* mp = mixT + (size_t)tile * 2048 + lane * 8;
        short8 b[4];
        #pragma unroll
        for (int s = 0; s < 4; ++s)
            b[s] = *(const short8*)(mp + s * 512);

        f32x4 acc[8] = {};
        #pragma unroll
        for (int s = 0; s < 4; ++s)
            #pragma unroll
            for (int jf = 0; jf < 8; ++jf)
                acc[jf] = __builtin_amdgcn_mfma_f32_16x16x32_bf16(a[jf][s], b[s], acc[jf], 0, 0, 0);

        #pragma unroll
        for (int f = 0; f < 8; ++f) {
            fv4 o;
            o.x = fmaxf(acc[f][0] + bi[f].x + h[f].x, 0.f);
            o.y = fmaxf(acc[f][1] + bi[f].y + h[f].y, 0.f);
            o.z = fmaxf(acc[f][2] + bi[f].z + h[f].z, 0.f);
            o.w = fmaxf(acc[f][3] + bi[f].w + h[f].w, 0.f);
            *(fv4*)(out + (size_t)tokr * 1024 + e0 + f * 16 + 4 * g) = o;
        }
    }
}

extern "C" void kernel_launch(void* const* d_in, const int* in_sizes, int n_in,
                              void* d_out, int out_size, void* d_ws, size_t ws_size,
                              hipStream_t stream) {
    const float* h0    = (const float*)d_in[0];
    const float* we0_w = (const float*)d_in[1];
    const float* we0_b = (const float*)d_in[2];
    const float* ws_w  = (const float*)d_in[3];
    const float* ws_b  = (const float*)d_in[4];
    const float* wm_w  = (const float*)d_in[5];
    const float* wm_b  = (const float*)d_in[6];
    const float* we1_w = (const float*)d_in[7];
    const float* we1_b = (const float*)d_in[8];
    float* out = (float*)d_out;

    unsigned short* wmb   = (unsigned short*)d_ws;      // 128*128*128
    unsigned short* we0b  = wmb  + 2097152;             // 128*1024
    unsigned short* we1b  = we0b + 131072;              // 1024*128
    unsigned short* wsb   = we1b + 131072;              // 128*128
    unsigned short* encT  = wsb  + 16384;               // 16384*128 (tiled)
    float*          logT  = (float*)(encT + 2097152);   // [128][16384]
    unsigned short* gateT = (unsigned short*)(logT + 2097152); // tiled
    unsigned short* mixT  = gateT + 2097152;            // tiled

    k_convert_all<<<640, 256, 0, stream>>>(wm_w, we0_w, we1_w, ws_w, wmb);
    k_enc<<<512, 256, 0, stream>>>(h0, we0b, wsb, we0_b, ws_b, encT, logT);
    k_softmax0<<<128, 256, 0, stream>>>(logT, gateT);
    k_mix<<<1024, 256, 0, stream>>>(wmb, encT, gateT, wm_b, mixT);
    k_dec<<<512, 256, 0, stream>>>(we1b, mixT, we1_b, h0, out);
}

// Round 5
// 173.885 us; speedup vs baseline: 2.0200x; 1.0674x over previous
//
#include <hip/hip_runtime.h>

// DomDepResidualLayer: out = relu(h0 + (mixed @ we1^T + b1))
//   enc   = h0 @ we0^T + b0                         [16384,128]
//   acts  = relu(einsum('nd,mkd->mnk', enc, wm)+bm) (never materialized)
//   gate  = softmax(enc @ ws^T + bs, axis=0)        [16384,128]
//   mixed[n,i] = sum_j acts[i,n,j]*gate[n,j]        [16384,128]
// v6: k_mix restructured for cross-wave MFMA/VALU overlap: no sw pipeline,
// grid 512 (tg=bid&3 -> whole XCD shares one tg slice; 2 blocks/CU, 1 pass),
// lean ~242-reg budget so 2 waves/SIMD hold without spill.

#define N_TOK   16384
#define EMB     1024
#define MDIM    128

typedef __attribute__((ext_vector_type(8))) short   short8;   // 8 bf16 = 1 MFMA frag
typedef __attribute__((ext_vector_type(4))) float   f32x4;
typedef __attribute__((ext_vector_type(4))) float   fv4;
typedef __attribute__((ext_vector_type(4))) unsigned short us4;

static __device__ __forceinline__ unsigned short f2bf(float f) {
    union { float f; unsigned u; } v; v.f = f;
    unsigned r = v.u + 0x7FFFu + ((v.u >> 16) & 1u);   // RNE
    return (unsigned short)(r >> 16);
}
static __device__ __forceinline__ float bf2f_lo(unsigned u) {
    union { unsigned u; float f; } v; v.u = u << 16; return v.f;
}
static __device__ __forceinline__ float bf2f_hi(unsigned u) {
    union { unsigned u; float f; } v; v.u = u & 0xffff0000u; return v.f;
}

// ---------------- fused fp32 -> bf16 conversion of all weights ----------------
__global__ void k_convert_all(const float* __restrict__ wm_w,
                              const float* __restrict__ we0_w,
                              const float* __restrict__ we1_w,
                              const float* __restrict__ ws_w,
                              unsigned short* __restrict__ dst) {
    const int NFV4 = 593920;
    for (int i = blockIdx.x * blockDim.x + threadIdx.x; i < NFV4;
         i += gridDim.x * blockDim.x) {
        const float* src;
        if (i < 524288)       src = wm_w  + (size_t)i * 4;
        else if (i < 557056)  src = we0_w + (size_t)(i - 524288) * 4;
        else if (i < 589824)  src = we1_w + (size_t)(i - 557056) * 4;
        else                  src = ws_w  + (size_t)(i - 589824) * 4;
        fv4 v = *(const fv4*)src;
        us4 o;
        o.x = f2bf(v.x); o.y = f2bf(v.y); o.z = f2bf(v.z); o.w = f2bf(v.w);
        *(us4*)(dst + (size_t)i * 4) = o;
    }
}

// Fragment-tiled bf16 layout for a [N,128] matrix X (2048 bf16 per 16-tok tile):
//   offset(tok,d) = (tok>>4)*2048 + (d>>5)*512 + (((d&31)>>3)*16 + (tok&15))*8 + (d&7)

// ---------------- enc = h0 @ we0^T + b0, fused logits^T = enc @ ws^T + bs ----------------
__global__ __launch_bounds__(256) void k_enc(const float* __restrict__ h0,
                                             const unsigned short* __restrict__ we0b,
                                             const unsigned short* __restrict__ wsb,
                                             const float* __restrict__ we0_bias,
                                             const float* __restrict__ ws_bias,
                                             unsigned short* __restrict__ encT,
                                             float* __restrict__ logT) {
    __shared__ unsigned short Wt[128 * 128];
    __shared__ unsigned short Ht[32 * 128];
    __shared__ unsigned short Et[32 * 128];

    const int tid = threadIdx.x;
    const int lane = tid & 63, w = tid >> 6;
    const int c = lane & 15, g = lane >> 4;
    const int wd = w >> 1, wt = w & 1;
    const int t0 = blockIdx.x * 32;

    f32x4 acc[4] = {};
    for (int ks = 0; ks < 8; ++ks) {
        #pragma unroll
        for (int it = 0; it < 8; ++it) {
            int m = it * 256 + tid;
            int row = m >> 4, gc = m & 15;
            short8 v = *(const short8*)(we0b + row * 1024 + ks * 128 + gc * 8);
            *(short8*)&Wt[row * 128 + ((gc ^ (row & 7)) * 8)] = v;
        }
        #pragma unroll
        for (int it = 0; it < 2; ++it) {
            int m = it * 256 + tid;
            int row = m >> 4, gc = m & 15;
            const float* hp = h0 + (size_t)(t0 + row) * 1024 + ks * 128 + gc * 8;
            fv4 v0 = *(const fv4*)hp;
            fv4 v1 = *(const fv4*)(hp + 4);
            short8 ov;
            ov[0] = (short)f2bf(v0.x); ov[1] = (short)f2bf(v0.y);
            ov[2] = (short)f2bf(v0.z); ov[3] = (short)f2bf(v0.w);
            ov[4] = (short)f2bf(v1.x); ov[5] = (short)f2bf(v1.y);
            ov[6] = (short)f2bf(v1.z); ov[7] = (short)f2bf(v1.w);
            *(short8*)&Ht[row * 128 + ((gc ^ (row & 7)) * 8)] = ov;
        }
        __syncthreads();
        #pragma unroll
        for (int s = 0; s < 4; ++s) {
            int gk = s * 4 + g;
            int brow = wt * 16 + c;
            short8 b = *(const short8*)&Ht[brow * 128 + ((gk ^ (brow & 7)) * 8)];
            #pragma unroll
            for (int jf = 0; jf < 4; ++jf) {
                int j = wd * 64 + jf * 16 + c;
                short8 a = *(const short8*)&Wt[j * 128 + ((gk ^ (j & 7)) * 8)];
                acc[jf] = __builtin_amdgcn_mfma_f32_16x16x32_bf16(a, b, acc[jf], 0, 0, 0);
            }
        }
        __syncthreads();
    }
    const int tile = blockIdx.x * 2 + wt;
    const int erow = wt * 16 + c;
    #pragma unroll
    for (int f = 0; f < 4; ++f) {
        int d0 = wd * 64 + f * 16 + 4 * g;
        int s = wd * 2 + (f >> 1);
        int chunk = ((f & 1) ? 2 : 0) + (g >> 1);
        int e = (g & 1) * 4;
        fv4 bi = *(const fv4*)(we0_bias + d0);
        us4 o;
        o.x = f2bf(acc[f][0] + bi.x);
        o.y = f2bf(acc[f][1] + bi.y);
        o.z = f2bf(acc[f][2] + bi.z);
        o.w = f2bf(acc[f][3] + bi.w);
        *(us4*)(encT + (size_t)tile * 2048 + s * 512 + (chunk * 16 + c) * 8 + e) = o;
        int cg = d0 >> 3, off = d0 & 7;
        *(us4*)&Et[erow * 128 + ((cg ^ (erow & 7)) * 8) + off] = o;
    }
    __syncthreads();

    short8 al[4][4];
    #pragma unroll
    for (int jf = 0; jf < 4; ++jf)
        #pragma unroll
        for (int s = 0; s < 4; ++s)
            al[jf][s] = *(const short8*)(wsb + (wd * 64 + jf * 16 + c) * 128 + s * 32 + g * 8);
    short8 bl[4];
    #pragma unroll
    for (int s = 0; s < 4; ++s) {
        int cg2 = s * 4 + g;
        bl[s] = *(const short8*)&Et[erow * 128 + ((cg2 ^ (erow & 7)) * 8)];
    }
    f32x4 acc2[4] = {};
    #pragma unroll
    for (int s = 0; s < 4; ++s)
        #pragma unroll
        for (int jf = 0; jf < 4; ++jf)
            acc2[jf] = __builtin_amdgcn_mfma_f32_16x16x32_bf16(al[jf][s], bl[s], acc2[jf], 0, 0, 0);
    const int tokc = t0 + wt * 16 + c;
    #pragma unroll
    for (int jf = 0; jf < 4; ++jf) {
        int m0 = wd * 64 + jf * 16 + 4 * g;
        fv4 bs = *(const fv4*)(ws_bias + m0);
        logT[(size_t)(m0 + 0) * N_TOK + tokc] = acc2[jf][0] + bs.x;
        logT[(size_t)(m0 + 1) * N_TOK + tokc] = acc2[jf][1] + bs.y;
        logT[(size_t)(m0 + 2) * N_TOK + tokc] = acc2[jf][2] + bs.z;
        logT[(size_t)(m0 + 3) * N_TOK + tokc] = acc2[jf][3] + bs.w;
    }
}

// ---------------- gate = softmax over axis 0, per column m ----------------
__global__ __launch_bounds__(256) void k_softmax0(const float* __restrict__ logT,
                                                  unsigned short* __restrict__ gateT) {
    __shared__ float red[8];
    const int m = blockIdx.x;
    const int tid = threadIdx.x;
    const int lane = tid & 63, wv = tid >> 6;
    const float* row = logT + (size_t)m * N_TOK;

    fv4 v[16];
    float vmax = -3.0e38f;
    #pragma unroll
    for (int it = 0; it < 16; ++it) {
        v[it] = *(const fv4*)(row + it * 1024 + tid * 4);
        vmax = fmaxf(vmax, fmaxf(fmaxf(v[it].x, v[it].y), fmaxf(v[it].z, v[it].w)));
    }
    #pragma unroll
    for (int o = 32; o > 0; o >>= 1) vmax = fmaxf(vmax, __shfl_xor(vmax, o));
    if (lane == 0) red[wv] = vmax;
    __syncthreads();
    const float bmax = fmaxf(fmaxf(red[0], red[1]), fmaxf(red[2], red[3]));

    float s = 0.f;
    #pragma unroll
    for (int it = 0; it < 16; ++it) {
        v[it].x = __expf(v[it].x - bmax); v[it].y = __expf(v[it].y - bmax);
        v[it].z = __expf(v[it].z - bmax); v[it].w = __expf(v[it].w - bmax);
        s += v[it].x + v[it].y + v[it].z + v[it].w;
    }
    #pragma unroll
    for (int o = 32; o > 0; o >>= 1) s += __shfl_xor(s, o);
    if (lane == 0) red[4 + wv] = s;
    __syncthreads();
    const float inv = 1.f / (red[4] + red[5] + red[6] + red[7]);

    const int q  = m >> 5;
    const int w8 = ((m >> 4) & 1) * 4 + (m & 3);
    const int gl = ((m & 15) >> 2) * 16;
    #pragma unroll
    for (int it = 0; it < 16; ++it) {
        int t = it * 1024 + tid * 4;
        float pv[4] = { v[it].x * inv, v[it].y * inv, v[it].z * inv, v[it].w * inv };
        #pragma unroll
        for (int k = 0; k < 4; ++k) {
            int tok = t + k;
            gateT[(size_t)(tok >> 4) * 2048 + q * 512 + (gl + (tok & 15)) * 8 + w8] = f2bf(pv[k]);
        }
    }
}

// ---------------- mixed[n][i] = sum_j relu(enc@wm[i]^T + bm)[n][j] * gate[n][j] ----------------
// grid 512: tg = bid&3 (4096 tokens), i = bid>>2. All blocks on an XCD share
// one tg slice (L2-resident); the CU's 2 co-resident blocks share per-rr tiles
// in L1. No sw pipeline: cross-wave MFMA/VALU overlap hides load+epilogue.
__global__ __launch_bounds__(256)
__attribute__((amdgpu_waves_per_eu(2, 2)))
void k_mix(const unsigned short* __restrict__ wmb,
           const unsigned short* __restrict__ encT,
           const unsigned short* __restrict__ gateT,
           const float* __restrict__ wm_bias,
           unsigned short* __restrict__ mixT) {
    const int bid = blockIdx.x;
    const int tg = bid & 3, i = bid >> 2;
    const int tid = threadIdx.x;
    const int lane = tid & 63, w = tid >> 6;
    const int c = lane & 15, g = lane >> 4;

    const unsigned short* wmi = wmb + (size_t)i * 16384;
    short8 a[8][4];
    #pragma unroll
    for (int jf = 0; jf < 8; ++jf)
        #pragma unroll
        for (int s = 0; s < 4; ++s) {
            a[jf][s] = *(const short8*)(wmi + (jf * 16 + c) * 128 + s * 32 + g * 8);
            asm volatile("" : "+v"(a[jf][s]));
        }
    f32x4 bias4[8];
    #pragma unroll
    for (int f = 0; f < 8; ++f)
        bias4[f] = *(const f32x4*)(wm_bias + i * 128 + f * 16 + 4 * g);

    const int si = i >> 5, ch = (i & 31) >> 3, ei = i & 7;

    #pragma unroll 1
    for (int rr = 0; rr < 64; ++rr) {
        const int tile = tg * 256 + rr * 4 + w;
        const unsigned short* ep = encT + (size_t)tile * 2048 + lane * 8;
        short8 b0 = *(const short8*)(ep);
        short8 b1 = *(const short8*)(ep + 512);
        short8 b2 = *(const short8*)(ep + 1024);
        short8 b3 = *(const short8*)(ep + 1536);
        const unsigned* gp = (const unsigned*)(gateT + (size_t)tile * 2048) + lane * 4;
        uint4 G0 = *(const uint4*)(gp);
        uint4 G1 = *(const uint4*)(gp + 256);
        uint4 G2 = *(const uint4*)(gp + 512);
        uint4 G3 = *(const uint4*)(gp + 768);

        f32x4 acc[8];
        #pragma unroll
        for (int jf = 0; jf < 8; ++jf)
            acc[jf] = __builtin_amdgcn_mfma_f32_16x16x32_bf16(a[jf][0], b0, bias4[jf], 0, 0, 0);
        #pragma unroll
        for (int jf = 0; jf < 8; ++jf)
            acc[jf] = __builtin_amdgcn_mfma_f32_16x16x32_bf16(a[jf][1], b1, acc[jf], 0, 0, 0);
        #pragma unroll
        for (int jf = 0; jf < 8; ++jf)
            acc[jf] = __builtin_amdgcn_mfma_f32_16x16x32_bf16(a[jf][2], b2, acc[jf], 0, 0, 0);
        #pragma unroll
        for (int jf = 0; jf < 8; ++jf)
            acc[jf] = __builtin_amdgcn_mfma_f32_16x16x32_bf16(a[jf][3], b3, acc[jf], 0, 0, 0);

        float p0 = 0.f, p1 = 0.f, p2 = 0.f, p3 = 0.f;
        #define EPI(F, GA, GB) {                                        \
            p0 += fmaxf(acc[F][0], 0.f) * bf2f_lo(GA);                  \
            p1 += fmaxf(acc[F][1], 0.f) * bf2f_hi(GA);                  \
            p2 += fmaxf(acc[F][2], 0.f) * bf2f_lo(GB);                  \
            p3 += fmaxf(acc[F][3], 0.f) * bf2f_hi(GB);                  \
        }
        EPI(0, G0.x, G0.y) EPI(1, G0.z, G0.w)
        EPI(2, G1.x, G1.y) EPI(3, G1.z, G1.w)
        EPI(4, G2.x, G2.y) EPI(5, G2.z, G2.w)
        EPI(6, G3.x, G3.y) EPI(7, G3.z, G3.w)
        #undef EPI
        float p = (p0 + p1) + (p2 + p3);
        p += __shfl_xor(p, 16);
        p += __shfl_xor(p, 32);
        if (lane < 16)
            mixT[(size_t)tile * 2048 + si * 512 + (ch * 16 + lane) * 8 + ei] = f2bf(p);
    }
}

// ---------------- out = relu(mixed @ we1^T + b1 + h0) ----------------
__global__ __launch_bounds__(256)
__attribute__((amdgpu_waves_per_eu(2, 2)))
void k_dec(const unsigned short* __restrict__ we1b,
           const unsigned short* __restrict__ mixT,
           const float* __restrict__ we1_bias,
           const float* __restrict__ h0,
           float* __restrict__ out) {
    const int bid = blockIdx.x;
    const int eb = bid & 7, tg = bid >> 3;
    const int e0 = eb * 128;
    const int tid = threadIdx.x;
    const int lane = tid & 63, w = tid >> 6;
    const int c = lane & 15, g = lane >> 4;

    short8 a[8][4];
    #pragma unroll
    for (int jf = 0; jf < 8; ++jf)
        #pragma unroll
        for (int s = 0; s < 4; ++s) {
            a[jf][s] = *(const short8*)(we1b + (size_t)(e0 + jf * 16 + c) * 128 + s * 32 + g * 8);
            asm volatile("" : "+v"(a[jf][s]));
        }
    fv4 bi[8];
    #pragma unroll
    for (int f = 0; f < 8; ++f)
        bi[f] = *(const fv4*)(we1_bias + e0 + f * 16 + 4 * g);

    #pragma unroll 1
    for (int t = 0; t < 4; ++t) {
        const int tokr = tg * 256 + t * 64 + w * 16 + c;
        const int tile = tg * 16 + t * 4 + w;
        fv4 h[8];
        #pragma unroll
        for (int f = 0; f < 8; ++f)
            h[f] = *(const fv4*)(h0 + (size_t)tokr * 1024 + e0 + f * 16 + 4 * g);
        const unsigned short* mp = mixT + (size_t)tile * 2048 + lane * 8;
        short8 b[4];
        #pragma unroll
        for (int s = 0; s < 4; ++s)
            b[s] = *(const short8*)(mp + s * 512);

        f32x4 acc[8] = {};
        #pragma unroll
        for (int s = 0; s < 4; ++s)
            #pragma unroll
            for (int jf = 0; jf < 8; ++jf)
                acc[jf] = __builtin_amdgcn_mfma_f32_16x16x32_bf16(a[jf][s], b[s], acc[jf], 0, 0, 0);

        #pragma unroll
        for (int f = 0; f < 8; ++f) {
            fv4 o;
            o.x = fmaxf(acc[f][0] + bi[f].x + h[f].x, 0.f);
            o.y = fmaxf(acc[f][1] + bi[f].y + h[f].y, 0.f);
            o.z = fmaxf(acc[f][2] + bi[f].z + h[f].z, 0.f);
            o.w = fmaxf(acc[f][3] + bi[f].w + h[f].w, 0.f);
            *(fv4*)(out + (size_t)tokr * 1024 + e0 + f * 16 + 4 * g) = o;
        }
    }
}

extern "C" void kernel_launch(void* const* d_in, const int* in_sizes, int n_in,
                              void* d_out, int out_size, void* d_ws, size_t ws_size,
                              hipStream_t stream) {
    const float* h0    = (const float*)d_in[0];
    const float* we0_w = (const float*)d_in[1];
    const float* we0_b = (const float*)d_in[2];
    const float* ws_w  = (const float*)d_in[3];
    const float* ws_b  = (const float*)d_in[4];
    const float* wm_w  = (const float*)d_in[5];
    const float* wm_b  = (const float*)d_in[6];
    const float* we1_w = (const float*)d_in[7];
    const float* we1_b = (const float*)d_in[8];
    float* out = (float*)d_out;

    unsigned short* wmb   = (unsigned short*)d_ws;      // 128*128*128
    unsigned short* we0b  = wmb  + 2097152;             // 128*1024
    unsigned short* we1b  = we0b + 131072;              // 1024*128
    unsigned short* wsb   = we1b + 131072;              // 128*128
    unsigned short* encT  = wsb  + 16384;               // 16384*128 (tiled)
    float*          logT  = (float*)(encT + 2097152);   // [128][16384]
    unsigned short* gateT = (unsigned short*)(logT + 2097152); // tiled
    unsigned short* mixT  = gateT + 2097152;            // tiled

    k_convert_all<<<640, 256, 0, stream>>>(wm_w, we0_w, we1_w, ws_w, wmb);
    k_enc<<<512, 256, 0, stream>>>(h0, we0b, wsb, we0_b, ws_b, encT, logT);
    k_softmax0<<<128, 256, 0, stream>>>(logT, gateT);
    k_mix<<<512, 256, 0, stream>>>(wmb, encT, gateT, wm_b, mixT);
    k_dec<<<512, 256, 0, stream>>>(we1b, mixT, we1_b, h0, out);
}

// Round 6
// 168.109 us; speedup vs baseline: 2.0894x; 1.0344x over previous
//
#include <hip/hip_runtime.h>

// DomDepResidualLayer: out = relu(h0 + (mixed @ we1^T + b1))
//   enc   = h0 @ we0^T + b0                         [16384,128]
//   acts  = relu(einsum('nd,mkd->mnk', enc, wm)+bm) (never materialized)
//   gate  = softmax(enc @ ws^T + bs, axis=0)        [16384,128]
//   mixed[n,i] = sum_j acts[i,n,j]*gate[n,j]        [16384,128]
// v7: k_mix with issue-early/consume-late pipeline: next-tile b-frags issued
// right AFTER the MFMA block (latency hides under epilogue), gate words
// ping-ponged inside the epilogue, setprio(1) around the MFMA cluster.

#define N_TOK   16384
#define EMB     1024
#define MDIM    128

typedef __attribute__((ext_vector_type(8))) short   short8;   // 8 bf16 = 1 MFMA frag
typedef __attribute__((ext_vector_type(4))) float   f32x4;
typedef __attribute__((ext_vector_type(4))) float   fv4;
typedef __attribute__((ext_vector_type(4))) unsigned short us4;

static __device__ __forceinline__ unsigned short f2bf(float f) {
    union { float f; unsigned u; } v; v.f = f;
    unsigned r = v.u + 0x7FFFu + ((v.u >> 16) & 1u);   // RNE
    return (unsigned short)(r >> 16);
}
static __device__ __forceinline__ float bf2f_lo(unsigned u) {
    union { unsigned u; float f; } v; v.u = u << 16; return v.f;
}
static __device__ __forceinline__ float bf2f_hi(unsigned u) {
    union { unsigned u; float f; } v; v.u = u & 0xffff0000u; return v.f;
}

// ---------------- fused fp32 -> bf16 conversion of all weights ----------------
__global__ void k_convert_all(const float* __restrict__ wm_w,
                              const float* __restrict__ we0_w,
                              const float* __restrict__ we1_w,
                              const float* __restrict__ ws_w,
                              unsigned short* __restrict__ dst) {
    const int NFV4 = 593920;
    for (int i = blockIdx.x * blockDim.x + threadIdx.x; i < NFV4;
         i += gridDim.x * blockDim.x) {
        const float* src;
        if (i < 524288)       src = wm_w  + (size_t)i * 4;
        else if (i < 557056)  src = we0_w + (size_t)(i - 524288) * 4;
        else if (i < 589824)  src = we1_w + (size_t)(i - 557056) * 4;
        else                  src = ws_w  + (size_t)(i - 589824) * 4;
        fv4 v = *(const fv4*)src;
        us4 o;
        o.x = f2bf(v.x); o.y = f2bf(v.y); o.z = f2bf(v.z); o.w = f2bf(v.w);
        *(us4*)(dst + (size_t)i * 4) = o;
    }
}

// Fragment-tiled bf16 layout for a [N,128] matrix X (2048 bf16 per 16-tok tile):
//   offset(tok,d) = (tok>>4)*2048 + (d>>5)*512 + (((d&31)>>3)*16 + (tok&15))*8 + (d&7)

// ---------------- enc = h0 @ we0^T + b0, fused logits^T = enc @ ws^T + bs ----------------
__global__ __launch_bounds__(256) void k_enc(const float* __restrict__ h0,
                                             const unsigned short* __restrict__ we0b,
                                             const unsigned short* __restrict__ wsb,
                                             const float* __restrict__ we0_bias,
                                             const float* __restrict__ ws_bias,
                                             unsigned short* __restrict__ encT,
                                             float* __restrict__ logT) {
    __shared__ unsigned short Wt[128 * 128];
    __shared__ unsigned short Ht[32 * 128];
    __shared__ unsigned short Et[32 * 128];

    const int tid = threadIdx.x;
    const int lane = tid & 63, w = tid >> 6;
    const int c = lane & 15, g = lane >> 4;
    const int wd = w >> 1, wt = w & 1;
    const int t0 = blockIdx.x * 32;

    f32x4 acc[4] = {};
    for (int ks = 0; ks < 8; ++ks) {
        #pragma unroll
        for (int it = 0; it < 8; ++it) {
            int m = it * 256 + tid;
            int row = m >> 4, gc = m & 15;
            short8 v = *(const short8*)(we0b + row * 1024 + ks * 128 + gc * 8);
            *(short8*)&Wt[row * 128 + ((gc ^ (row & 7)) * 8)] = v;
        }
        #pragma unroll
        for (int it = 0; it < 2; ++it) {
            int m = it * 256 + tid;
            int row = m >> 4, gc = m & 15;
            const float* hp = h0 + (size_t)(t0 + row) * 1024 + ks * 128 + gc * 8;
            fv4 v0 = *(const fv4*)hp;
            fv4 v1 = *(const fv4*)(hp + 4);
            short8 ov;
            ov[0] = (short)f2bf(v0.x); ov[1] = (short)f2bf(v0.y);
            ov[2] = (short)f2bf(v0.z); ov[3] = (short)f2bf(v0.w);
            ov[4] = (short)f2bf(v1.x); ov[5] = (short)f2bf(v1.y);
            ov[6] = (short)f2bf(v1.z); ov[7] = (short)f2bf(v1.w);
            *(short8*)&Ht[row * 128 + ((gc ^ (row & 7)) * 8)] = ov;
        }
        __syncthreads();
        #pragma unroll
        for (int s = 0; s < 4; ++s) {
            int gk = s * 4 + g;
            int brow = wt * 16 + c;
            short8 b = *(const short8*)&Ht[brow * 128 + ((gk ^ (brow & 7)) * 8)];
            #pragma unroll
            for (int jf = 0; jf < 4; ++jf) {
                int j = wd * 64 + jf * 16 + c;
                short8 a = *(const short8*)&Wt[j * 128 + ((gk ^ (j & 7)) * 8)];
                acc[jf] = __builtin_amdgcn_mfma_f32_16x16x32_bf16(a, b, acc[jf], 0, 0, 0);
            }
        }
        __syncthreads();
    }
    const int tile = blockIdx.x * 2 + wt;
    const int erow = wt * 16 + c;
    #pragma unroll
    for (int f = 0; f < 4; ++f) {
        int d0 = wd * 64 + f * 16 + 4 * g;
        int s = wd * 2 + (f >> 1);
        int chunk = ((f & 1) ? 2 : 0) + (g >> 1);
        int e = (g & 1) * 4;
        fv4 bi = *(const fv4*)(we0_bias + d0);
        us4 o;
        o.x = f2bf(acc[f][0] + bi.x);
        o.y = f2bf(acc[f][1] + bi.y);
        o.z = f2bf(acc[f][2] + bi.z);
        o.w = f2bf(acc[f][3] + bi.w);
        *(us4*)(encT + (size_t)tile * 2048 + s * 512 + (chunk * 16 + c) * 8 + e) = o;
        int cg = d0 >> 3, off = d0 & 7;
        *(us4*)&Et[erow * 128 + ((cg ^ (erow & 7)) * 8) + off] = o;
    }
    __syncthreads();

    short8 al[4][4];
    #pragma unroll
    for (int jf = 0; jf < 4; ++jf)
        #pragma unroll
        for (int s = 0; s < 4; ++s)
            al[jf][s] = *(const short8*)(wsb + (wd * 64 + jf * 16 + c) * 128 + s * 32 + g * 8);
    short8 bl[4];
    #pragma unroll
    for (int s = 0; s < 4; ++s) {
        int cg2 = s * 4 + g;
        bl[s] = *(const short8*)&Et[erow * 128 + ((cg2 ^ (erow & 7)) * 8)];
    }
    f32x4 acc2[4] = {};
    #pragma unroll
    for (int s = 0; s < 4; ++s)
        #pragma unroll
        for (int jf = 0; jf < 4; ++jf)
            acc2[jf] = __builtin_amdgcn_mfma_f32_16x16x32_bf16(al[jf][s], bl[s], acc2[jf], 0, 0, 0);
    const int tokc = t0 + wt * 16 + c;
    #pragma unroll
    for (int jf = 0; jf < 4; ++jf) {
        int m0 = wd * 64 + jf * 16 + 4 * g;
        fv4 bs = *(const fv4*)(ws_bias + m0);
        logT[(size_t)(m0 + 0) * N_TOK + tokc] = acc2[jf][0] + bs.x;
        logT[(size_t)(m0 + 1) * N_TOK + tokc] = acc2[jf][1] + bs.y;
        logT[(size_t)(m0 + 2) * N_TOK + tokc] = acc2[jf][2] + bs.z;
        logT[(size_t)(m0 + 3) * N_TOK + tokc] = acc2[jf][3] + bs.w;
    }
}

// ---------------- gate = softmax over axis 0, per column m ----------------
__global__ __launch_bounds__(256) void k_softmax0(const float* __restrict__ logT,
                                                  unsigned short* __restrict__ gateT) {
    __shared__ float red[8];
    const int m = blockIdx.x;
    const int tid = threadIdx.x;
    const int lane = tid & 63, wv = tid >> 6;
    const float* row = logT + (size_t)m * N_TOK;

    fv4 v[16];
    float vmax = -3.0e38f;
    #pragma unroll
    for (int it = 0; it < 16; ++it) {
        v[it] = *(const fv4*)(row + it * 1024 + tid * 4);
        vmax = fmaxf(vmax, fmaxf(fmaxf(v[it].x, v[it].y), fmaxf(v[it].z, v[it].w)));
    }
    #pragma unroll
    for (int o = 32; o > 0; o >>= 1) vmax = fmaxf(vmax, __shfl_xor(vmax, o));
    if (lane == 0) red[wv] = vmax;
    __syncthreads();
    const float bmax = fmaxf(fmaxf(red[0], red[1]), fmaxf(red[2], red[3]));

    float s = 0.f;
    #pragma unroll
    for (int it = 0; it < 16; ++it) {
        v[it].x = __expf(v[it].x - bmax); v[it].y = __expf(v[it].y - bmax);
        v[it].z = __expf(v[it].z - bmax); v[it].w = __expf(v[it].w - bmax);
        s += v[it].x + v[it].y + v[it].z + v[it].w;
    }
    #pragma unroll
    for (int o = 32; o > 0; o >>= 1) s += __shfl_xor(s, o);
    if (lane == 0) red[4 + wv] = s;
    __syncthreads();
    const float inv = 1.f / (red[4] + red[5] + red[6] + red[7]);

    const int q  = m >> 5;
    const int w8 = ((m >> 4) & 1) * 4 + (m & 3);
    const int gl = ((m & 15) >> 2) * 16;
    #pragma unroll
    for (int it = 0; it < 16; ++it) {
        int t = it * 1024 + tid * 4;
        float pv[4] = { v[it].x * inv, v[it].y * inv, v[it].z * inv, v[it].w * inv };
        #pragma unroll
        for (int k = 0; k < 4; ++k) {
            int tok = t + k;
            gateT[(size_t)(tok >> 4) * 2048 + q * 512 + (gl + (tok & 15)) * 8 + w8] = f2bf(pv[k]);
        }
    }
}

// ---------------- mixed[n][i] = sum_j relu(enc@wm[i]^T + bm)[n][j] * gate[n][j] ----------------
// grid 512: tg = bid&3 (XCD-shared tg slice), i = bid>>2. Resident wm panel.
// Pipeline: MFMA(b_cur) -> issue b_next -> EPI(0..3,G01) -> issue G01_next
//           -> EPI(4..7,G23) -> store -> issue G23_next.
__global__ __launch_bounds__(256)
__attribute__((amdgpu_waves_per_eu(2, 2)))
void k_mix(const unsigned short* __restrict__ wmb,
           const unsigned short* __restrict__ encT,
           const unsigned short* __restrict__ gateT,
           const float* __restrict__ wm_bias,
           unsigned short* __restrict__ mixT) {
    const int bid = blockIdx.x;
    const int tg = bid & 3, i = bid >> 2;
    const int tid = threadIdx.x;
    const int lane = tid & 63, w = tid >> 6;
    const int c = lane & 15, g = lane >> 4;

    const unsigned short* wmi = wmb + (size_t)i * 16384;
    short8 a[8][4];
    #pragma unroll
    for (int jf = 0; jf < 8; ++jf)
        #pragma unroll
        for (int s = 0; s < 4; ++s) {
            a[jf][s] = *(const short8*)(wmi + (jf * 16 + c) * 128 + s * 32 + g * 8);
            asm volatile("" : "+v"(a[jf][s]));
        }
    f32x4 bias4[8];
    #pragma unroll
    for (int f = 0; f < 8; ++f)
        bias4[f] = *(const f32x4*)(wm_bias + i * 128 + f * 16 + 4 * g);

    const int si = i >> 5, ch = (i & 31) >> 3, ei = i & 7;

    // prologue: b, G for rr=0
    const unsigned short* ep0 = encT + (size_t)(tg * 256 + w) * 2048 + lane * 8;
    short8 b0 = *(const short8*)(ep0);
    short8 b1 = *(const short8*)(ep0 + 512);
    short8 b2 = *(const short8*)(ep0 + 1024);
    short8 b3 = *(const short8*)(ep0 + 1536);
    const unsigned* gp0 = (const unsigned*)(gateT + (size_t)(tg * 256 + w) * 2048) + lane * 4;
    uint4 G0 = *(const uint4*)(gp0);
    uint4 G1 = *(const uint4*)(gp0 + 256);
    uint4 G2 = *(const uint4*)(gp0 + 512);
    uint4 G3 = *(const uint4*)(gp0 + 768);

    #pragma unroll 1
    for (int rr = 0; rr < 64; ++rr) {
        const int tile = tg * 256 + rr * 4 + w;
        const int ntile = tg * 256 + ((rr < 63) ? rr + 1 : 63) * 4 + w;

        __builtin_amdgcn_s_setprio(1);
        f32x4 acc[8];
        #pragma unroll
        for (int jf = 0; jf < 8; ++jf)
            acc[jf] = __builtin_amdgcn_mfma_f32_16x16x32_bf16(a[jf][0], b0, bias4[jf], 0, 0, 0);
        #pragma unroll
        for (int jf = 0; jf < 8; ++jf)
            acc[jf] = __builtin_amdgcn_mfma_f32_16x16x32_bf16(a[jf][1], b1, acc[jf], 0, 0, 0);
        #pragma unroll
        for (int jf = 0; jf < 8; ++jf)
            acc[jf] = __builtin_amdgcn_mfma_f32_16x16x32_bf16(a[jf][2], b2, acc[jf], 0, 0, 0);
        #pragma unroll
        for (int jf = 0; jf < 8; ++jf)
            acc[jf] = __builtin_amdgcn_mfma_f32_16x16x32_bf16(a[jf][3], b3, acc[jf], 0, 0, 0);
        __builtin_amdgcn_s_setprio(0);

        // issue next-tile b loads: latency hides under the epilogue below
        const unsigned short* epn = encT + (size_t)ntile * 2048 + lane * 8;
        b0 = *(const short8*)(epn);
        b1 = *(const short8*)(epn + 512);
        b2 = *(const short8*)(epn + 1024);
        b3 = *(const short8*)(epn + 1536);

        float p0 = 0.f, p1 = 0.f, p2 = 0.f, p3 = 0.f;
        #define EPI(F, GA, GB) {                                        \
            p0 += fmaxf(acc[F][0], 0.f) * bf2f_lo(GA);                  \
            p1 += fmaxf(acc[F][1], 0.f) * bf2f_hi(GA);                  \
            p2 += fmaxf(acc[F][2], 0.f) * bf2f_lo(GB);                  \
            p3 += fmaxf(acc[F][3], 0.f) * bf2f_hi(GB);                  \
        }
        EPI(0, G0.x, G0.y) EPI(1, G0.z, G0.w)
        EPI(2, G1.x, G1.y) EPI(3, G1.z, G1.w)

        // G0,G1 fully consumed -> issue their next-tile loads
        const unsigned* gpn = (const unsigned*)(gateT + (size_t)ntile * 2048) + lane * 4;
        G0 = *(const uint4*)(gpn);
        G1 = *(const uint4*)(gpn + 256);

        EPI(4, G2.x, G2.y) EPI(5, G2.z, G2.w)
        EPI(6, G3.x, G3.y) EPI(7, G3.z, G3.w)
        #undef EPI
        float p = (p0 + p1) + (p2 + p3);
        p += __shfl_xor(p, 16);
        p += __shfl_xor(p, 32);
        if (lane < 16)
            mixT[(size_t)tile * 2048 + si * 512 + (ch * 16 + lane) * 8 + ei] = f2bf(p);

        // G2,G3 consumed -> issue their next-tile loads
        G2 = *(const uint4*)(gpn + 512);
        G3 = *(const uint4*)(gpn + 768);
    }
}

// ---------------- out = relu(mixed @ we1^T + b1 + h0) ----------------
__global__ __launch_bounds__(256)
__attribute__((amdgpu_waves_per_eu(2, 2)))
void k_dec(const unsigned short* __restrict__ we1b,
           const unsigned short* __restrict__ mixT,
           const float* __restrict__ we1_bias,
           const float* __restrict__ h0,
           float* __restrict__ out) {
    const int bid = blockIdx.x;
    const int eb = bid & 7, tg = bid >> 3;
    const int e0 = eb * 128;
    const int tid = threadIdx.x;
    const int lane = tid & 63, w = tid >> 6;
    const int c = lane & 15, g = lane >> 4;

    short8 a[8][4];
    #pragma unroll
    for (int jf = 0; jf < 8; ++jf)
        #pragma unroll
        for (int s = 0; s < 4; ++s) {
            a[jf][s] = *(const short8*)(we1b + (size_t)(e0 + jf * 16 + c) * 128 + s * 32 + g * 8);
            asm volatile("" : "+v"(a[jf][s]));
        }
    fv4 bi[8];
    #pragma unroll
    for (int f = 0; f < 8; ++f)
        bi[f] = *(const fv4*)(we1_bias + e0 + f * 16 + 4 * g);

    #pragma unroll 1
    for (int t = 0; t < 4; ++t) {
        const int tokr = tg * 256 + t * 64 + w * 16 + c;
        const int tile = tg * 16 + t * 4 + w;
        fv4 h[8];
        #pragma unroll
        for (int f = 0; f < 8; ++f)
            h[f] = *(const fv4*)(h0 + (size_t)tokr * 1024 + e0 + f * 16 + 4 * g);
        const unsigned short* mp = mixT + (size_t)tile * 2048 + lane * 8;
        short8 b[4];
        #pragma unroll
        for (int s = 0; s < 4; ++s)
            b[s] = *(const short8*)(mp + s * 512);

        f32x4 acc[8] = {};
        #pragma unroll
        for (int s = 0; s < 4; ++s)
            #pragma unroll
            for (int jf = 0; jf < 8; ++jf)
                acc[jf] = __builtin_amdgcn_mfma_f32_16x16x32_bf16(a[jf][s], b[s], acc[jf], 0, 0, 0);

        #pragma unroll
        for (int f = 0; f < 8; ++f) {
            fv4 o;
            o.x = fmaxf(acc[f][0] + bi[f].x + h[f].x, 0.f);
            o.y = fmaxf(acc[f][1] + bi[f].y + h[f].y, 0.f);
            o.z = fmaxf(acc[f][2] + bi[f].z + h[f].z, 0.f);
            o.w = fmaxf(acc[f][3] + bi[f].w + h[f].w, 0.f);
            *(fv4*)(out + (size_t)tokr * 1024 + e0 + f * 16 + 4 * g) = o;
        }
    }
}

extern "C" void kernel_launch(void* const* d_in, const int* in_sizes, int n_in,
                              void* d_out, int out_size, void* d_ws, size_t ws_size,
                              hipStream_t stream) {
    const float* h0    = (const float*)d_in[0];
    const float* we0_w = (const float*)d_in[1];
    const float* we0_b = (const float*)d_in[2];
    const float* ws_w  = (const float*)d_in[3];
    const float* ws_b  = (const float*)d_in[4];
    const float* wm_w  = (const float*)d_in[5];
    const float* wm_b  = (const float*)d_in[6];
    const float* we1_w = (const float*)d_in[7];
    const float* we1_b = (const float*)d_in[8];
    float* out = (float*)d_out;

    unsigned short* wmb   = (unsigned short*)d_ws;      // 128*128*128
    unsigned short* we0b  = wmb  + 2097152;             // 128*1024
    unsigned short* we1b  = we0b + 131072;              // 1024*128
    unsigned short* wsb   = we1b + 131072;              // 128*128
    unsigned short* encT  = wsb  + 16384;               // 16384*128 (tiled)
    float*          logT  = (float*)(encT + 2097152);   // [128][16384]
    unsigned short* gateT = (unsigned short*)(logT + 2097152); // tiled
    unsigned short* mixT  = gateT + 2097152;            // tiled

    k_convert_all<<<640, 256, 0, stream>>>(wm_w, we0_w, we1_w, ws_w, wmb);
    k_enc<<<512, 256, 0, stream>>>(h0, we0b, wsb, we0_b, ws_b, encT, logT);
    k_softmax0<<<128, 256, 0, stream>>>(logT, gateT);
    k_mix<<<512, 256, 0, stream>>>(wmb, encT, gateT, wm_b, mixT);
    k_dec<<<512, 256, 0, stream>>>(we1b, mixT, we1_b, h0, out);
}